// Round 3
// baseline (44.840 us; speedup 1.0000x reference)
//
#include <hip/hip_runtime.h>

// SpatialCorrelationSampler(kernel=1, patch=2, stride=2): out[b,0,0,oh,ow] =
// sum_{c,ph,pw} in1[b,c,2oh+ph,2ow+pw] * in2[b,c,2oh+ph,2ow+pw]; other patch
// slots are zero. B=8, C=256, H=W=128, oH=oW=64.
//
// R2: same nt-streaming theory as R1; fixed the compile error by using a
// native clang ext_vector_type for __builtin_nontemporal_load (HIP's float4
// is a struct wrapper the builtin rejects).

#define B_  8
#define C_  256
#define H_  128
#define W_  128
#define OH_ 64
#define OW_ 64

typedef float fvec4 __attribute__((ext_vector_type(4)));

// 1024 threads = 16 waves/block; 2 blocks/CU -> 32 waves/CU.
__global__ __launch_bounds__(1024, 8) void
corr_kernel(const float* __restrict__ in1, const float* __restrict__ in2,
            float* __restrict__ out) {
    __shared__ float red[16][64];

    const int bid  = blockIdx.x;       // 0..511
    const int b    = bid >> 6;         // 0..7
    const int oh   = bid & 63;         // 0..63
    const int tid  = threadIdx.x;
    const int wid  = tid >> 6;         // wave 0..15 -> channel group
    const int lane = tid & 63;
    const int r    = lane >> 5;        // row within the 2x2 patch pair: 0/1
    const int q    = lane & 31;        // float4 index within the 128-col row

    // element offset of (b, c=wid, h=2*oh+r, w=4*q)
    size_t base = ((size_t)(b * C_ + wid) * H_ + (2 * oh + r)) * W_ + 4 * q;
    const size_t cstep = (size_t)16 * H_ * W_;   // +16 channels

    float acc0 = 0.f, acc1 = 0.f;                // ow = 2q, 2q+1 partials
    #pragma unroll
    for (int i = 0; i < 16; ++i) {
        // in1: non-temporal (stream, don't cache) -> leaves L3 to in2
        const fvec4 a = __builtin_nontemporal_load(
            reinterpret_cast<const fvec4*>(in1 + base + i * cstep));
        // in2: normal load -> L3-resident across replays
        const fvec4 v = *reinterpret_cast<const fvec4*>(in2 + base + i * cstep);
        acc0 += a.x * v.x + a.y * v.y;
        acc1 += a.z * v.z + a.w * v.w;
    }

    // lanes l and l^32 hold the two patch rows of the same ow pair
    acc0 += __shfl_xor(acc0, 32);
    acc1 += __shfl_xor(acc1, 32);
    if (r == 0) {
        red[wid][2 * q]     = acc0;
        red[wid][2 * q + 1] = acc1;
    }
    __syncthreads();

    if (tid < 64) {
        // sum the 16 per-wave partials for ow = tid
        float s = 0.f;
        #pragma unroll
        for (int wv = 0; wv < 16; ++wv) s += red[wv][tid];
        out[(size_t)(b * 4 + 0) * (OH_ * OW_) + oh * OW_ + tid] = s;
    } else if (tid < 256) {
        // zero patch slots (0,1),(1,0),(1,1) for this (b, oh) row
        const int slot = tid >> 6;     // 1..3
        out[(size_t)(b * 4 + slot) * (OH_ * OW_) + oh * OW_ + (tid & 63)] = 0.f;
    }
}

extern "C" void kernel_launch(void* const* d_in, const int* in_sizes, int n_in,
                              void* d_out, int out_size, void* d_ws, size_t ws_size,
                              hipStream_t stream) {
    const float* in1 = (const float*)d_in[0];
    const float* in2 = (const float*)d_in[1];
    float* out = (float*)d_out;
    dim3 grid(B_ * OH_);   // 512 blocks
    dim3 block(1024);
    corr_kernel<<<grid, block, 0, stream>>>(in1, in2, out);
}

// Round 4
// 43.493 us; speedup vs baseline: 1.0310x; 1.0310x over previous
//
#include <hip/hip_runtime.h>

// SpatialCorrelationSampler(kernel=1, patch=2, stride=2): out[b,0,0,oh,ow] =
// sum_{c,ph,pw} in1[b,c,2oh+ph,2ow+pw] * in2[b,c,2oh+ph,2ow+pw]; other patch
// slots are zero. B=8, C=256, H=W=128, oH=oW=64.
//
// R4: latency/MLP-bound, not HBM-bound (FETCH=131MB = half footprint ->
// HBM only at 3.1 TB/s; aggregate 6.16 TB/s limited by ~2.6KB in-flight/CU).
// Fix: batch 4 float4 loads per input into register arrays before the FMAs
// -> 8 outstanding 16B loads/thread (~4KB+/CU in flight). nt loads reverted
// (R3: null).

#define B_  8
#define C_  256
#define H_  128
#define W_  128
#define OH_ 64
#define OW_ 64

typedef float fvec4 __attribute__((ext_vector_type(4)));

// 1024 threads = 16 waves/block; 2 blocks/CU -> 32 waves/CU; VGPR cap 64.
__global__ __launch_bounds__(1024, 8) void
corr_kernel(const float* __restrict__ in1, const float* __restrict__ in2,
            float* __restrict__ out) {
    __shared__ float red[16][64];

    const int bid  = blockIdx.x;       // 0..511
    const int b    = bid >> 6;         // 0..7
    const int oh   = bid & 63;         // 0..63
    const int tid  = threadIdx.x;
    const int wid  = tid >> 6;         // wave 0..15 -> channel group
    const int lane = tid & 63;
    const int r    = lane >> 5;        // row within the 2x2 patch pair: 0/1
    const int q    = lane & 31;        // float4 index within the 128-col row

    // element offset of (b, c=wid, h=2*oh+r, w=4*q)
    const size_t base  = ((size_t)(b * C_ + wid) * H_ + (2 * oh + r)) * W_ + 4 * q;
    const size_t cstep = (size_t)16 * H_ * W_;   // +16 channels

    const float* p1 = in1 + base;
    const float* p2 = in2 + base;

    float acc0 = 0.f, acc1 = 0.f;                // ow = 2q, 2q+1 partials
    #pragma unroll
    for (int i = 0; i < 4; ++i) {
        fvec4 a[4], v[4];
        // issue 8 independent 16B loads before consuming any
        #pragma unroll
        for (int j = 0; j < 4; ++j) {
            a[j] = *reinterpret_cast<const fvec4*>(p1 + (size_t)(i * 4 + j) * cstep);
            v[j] = *reinterpret_cast<const fvec4*>(p2 + (size_t)(i * 4 + j) * cstep);
        }
        #pragma unroll
        for (int j = 0; j < 4; ++j) {
            acc0 += a[j].x * v[j].x + a[j].y * v[j].y;
            acc1 += a[j].z * v[j].z + a[j].w * v[j].w;
        }
    }

    // lanes l and l^32 hold the two patch rows of the same ow pair
    acc0 += __shfl_xor(acc0, 32);
    acc1 += __shfl_xor(acc1, 32);
    if (r == 0) {
        red[wid][2 * q]     = acc0;
        red[wid][2 * q + 1] = acc1;
    }
    __syncthreads();

    if (tid < 64) {
        // sum the 16 per-wave partials for ow = tid
        float s = 0.f;
        #pragma unroll
        for (int wv = 0; wv < 16; ++wv) s += red[wv][tid];
        out[(size_t)(b * 4 + 0) * (OH_ * OW_) + oh * OW_ + tid] = s;
    } else if (tid < 256) {
        // zero patch slots (0,1),(1,0),(1,1) for this (b, oh) row
        const int slot = tid >> 6;     // 1..3
        out[(size_t)(b * 4 + slot) * (OH_ * OW_) + oh * OW_ + (tid & 63)] = 0.f;
    }
}

extern "C" void kernel_launch(void* const* d_in, const int* in_sizes, int n_in,
                              void* d_out, int out_size, void* d_ws, size_t ws_size,
                              hipStream_t stream) {
    const float* in1 = (const float*)d_in[0];
    const float* in2 = (const float*)d_in[1];
    float* out = (float*)d_out;
    dim3 grid(B_ * OH_);   // 512 blocks
    dim3 block(1024);
    corr_kernel<<<grid, block, 0, stream>>>(in1, in2, out);
}